// Round 20
// baseline (263.404 us; speedup 1.0000x reference)
//
#include <hip/hip_runtime.h>

typedef _Float16 f16x8 __attribute__((ext_vector_type(8)));
typedef __fp16 fp16x2 __attribute__((ext_vector_type(2)));
typedef __attribute__((ext_vector_type(4))) float f32x4;

#define CC 256
#define SS 1024
#define KK 4
#define XR 6
#define XC 34
#define NCELL (XR * XC)  // 204

__device__ __forceinline__ unsigned int pk2h(float a, float b) {
  fp16x2 h = __builtin_amdgcn_cvt_pkrtz(a, b);
  return __builtin_bit_cast(unsigned int, h);
}

#define S_VMCNT0 asm volatile("s_waitcnt vmcnt(0)" ::: "memory")
#define S_LGKM0 asm volatile("s_waitcnt lgkmcnt(0)" ::: "memory")
#define SCHED0 __builtin_amdgcn_sched_barrier(0)

// qk[c][n] = sum_d Wk[c, n*64+d] * q[n, d]
__global__ void qk_kernel(const float* __restrict__ Wk, const float* __restrict__ q,
                          float* __restrict__ qk) {
  int t = blockIdx.x * blockDim.x + threadIdx.x;
  if (t >= CC * 2) return;
  int c = t >> 1, n = t & 1;
  float s = 0.f;
  for (int d = 0; d < 64; ++d) s += Wk[c * 128 + n * 64 + d] * q[n * 64 + d];
  qk[c * 2 + n] = s;
}

// One-time: all 4 experts' weights -> f16, transposed tiles:
// Wt[(e*72 + tile)*8192 + co*32 + ki]
__global__ void prep_w_kernel(const float* __restrict__ We, unsigned short* __restrict__ Wt) {
  int tile = blockIdx.x;  // 0..71 = tap*8+kc
  int e = blockIdx.y;
  int tap = tile >> 3, kc = tile & 7;
  int co = threadIdx.x;
  __shared__ float ts[32][257];
  const float* src = We + (size_t)(e * 9 + tap) * 65536 + (size_t)(kc * 32) * 256 + co;
  for (int ci = 0; ci < 32; ++ci) ts[ci][co] = src[(size_t)ci * 256];
  __syncthreads();
  unsigned int hw[16];
#pragma unroll
  for (int k2 = 0; k2 < 16; ++k2) hw[k2] = pk2h(ts[k2 * 2][co], ts[k2 * 2 + 1][co]);
  size_t base = ((size_t)e * 72 + tile) * 8192 + (size_t)co * 32;
#pragma unroll
  for (int j = 0; j < 4; ++j)
    *(uint4*)(Wt + base + j * 8) = make_uint4(hw[j * 4], hw[j * 4 + 1], hw[j * 4 + 2], hw[j * 4 + 3]);
}

// One pass over x per step: per (b, 64-pixel chunk) compute raw scores,
// chunk-local softmax stats (m, Z) and partial attn-weighted sums xa.
// part layout per (b,ch): [0]=m0 [1]=m1 [2]=Z0 [3]=Z1 [4..259]=xa0 [260..515]=xa1 (stride 520)
__global__ void poolpart_kernel(const float* __restrict__ x, const float* __restrict__ qk,
                                float* __restrict__ scores, float* __restrict__ part) {
  __shared__ float xs[64][260];
  __shared__ float ds[2][64];
  __shared__ float qks[512];
  int ch = blockIdx.x, b = blockIdx.y, tid = threadIdx.x;
  int s0 = ch * 64;
  const float* xb = x + ((size_t)b * 1024 + s0) * 256;
  for (int i = tid; i < 4096; i += 256) {
    int r = i >> 6, c4 = (i & 63) << 2;
    *(float4*)(&xs[r][c4]) = *(const float4*)(xb + (size_t)r * 256 + c4);
  }
  for (int i = tid; i < 512; i += 256) qks[i] = qk[i];
  __syncthreads();

  int p = tid >> 2, qd = tid & 3;
  float d0 = 0.f, d1 = 0.f;
  const float* xr = &xs[p][qd];
  const float* qr = qks + 2 * qd;
#pragma unroll 8
  for (int j = 0; j < 64; ++j) {
    float xv = xr[4 * j];
    d0 += xv * qr[8 * j];
    d1 += xv * qr[8 * j + 1];
  }
  d0 += __shfl_xor(d0, 1, 64); d0 += __shfl_xor(d0, 2, 64);
  d1 += __shfl_xor(d1, 1, 64); d1 += __shfl_xor(d1, 2, 64);
  if (qd == 0) {
    ds[0][p] = d0 * 0.125f;
    ds[1][p] = d1 * 0.125f;
    scores[((size_t)b * 2 + 0) * 1024 + s0 + p] = d0 * 0.125f;
    scores[((size_t)b * 2 + 1) * 1024 + s0 + p] = d1 * 0.125f;
  }
  __syncthreads();

  int lane = tid & 63, wv = tid >> 6;
  if (wv < 2) {
    float v = ds[wv][lane];
    float m = v;
#pragma unroll
    for (int sh = 32; sh >= 1; sh >>= 1) m = fmaxf(m, __shfl_xor(m, sh, 64));
    float e = expf(v - m);
    float Z = e;
#pragma unroll
    for (int sh = 32; sh >= 1; sh >>= 1) Z += __shfl_xor(Z, sh, 64);
    ds[wv][lane] = e;
    if (lane == 0) {
      float* o = part + ((size_t)(b * 16 + ch)) * 520;
      o[wv] = m;
      o[2 + wv] = Z;
    }
  }
  __syncthreads();
  float a0a = 0.f, a0b = 0.f, a0c = 0.f, a0d = 0.f;
  float a1a = 0.f, a1b = 0.f, a1c = 0.f, a1d = 0.f;
#pragma unroll 4
  for (int s4 = 0; s4 < 16; ++s4) {
    float x0 = xs[s4 * 4 + 0][tid];
    float x1 = xs[s4 * 4 + 1][tid];
    float x2 = xs[s4 * 4 + 2][tid];
    float x3 = xs[s4 * 4 + 3][tid];
    a0a += ds[0][s4 * 4 + 0] * x0;
    a0b += ds[0][s4 * 4 + 1] * x1;
    a0c += ds[0][s4 * 4 + 2] * x2;
    a0d += ds[0][s4 * 4 + 3] * x3;
    a1a += ds[1][s4 * 4 + 0] * x0;
    a1b += ds[1][s4 * 4 + 1] * x1;
    a1c += ds[1][s4 * 4 + 2] * x2;
    a1d += ds[1][s4 * 4 + 3] * x3;
  }
  float* o = part + ((size_t)(b * 16 + ch)) * 520;
  o[4 + tid] = (a0a + a0b) + (a0c + a0d);
  o[4 + 256 + tid] = (a1a + a1b) + (a1c + a1d);
}

// reconcile partials -> rowscale + pooled -> logits -> top-2 routing (fused)
__global__ void route_kernel(const float* __restrict__ part, const float* __restrict__ scores,
                             const float* __restrict__ Wv, const float* __restrict__ Wmlp,
                             const float* __restrict__ alpha, float* __restrict__ allowed,
                             float* __restrict__ rowscale,
                             int* __restrict__ selE, float* __restrict__ selW, int step) {
  __shared__ float xs[512];
  __shared__ float phalf[256];
  __shared__ float pooled[128];
  __shared__ float lg[4];
  __shared__ float Msh[2], iZsh[2];
  __shared__ float cs[2][16];
  int b = blockIdx.x, tid = threadIdx.x;
  if (tid < 2) {
    float m = -1e30f;
    for (int ch = 0; ch < 16; ++ch)
      m = fmaxf(m, part[((size_t)(b * 16 + ch)) * 520 + tid]);
    float z = 0.f;
    for (int ch = 0; ch < 16; ++ch) {
      const float* p = part + ((size_t)(b * 16 + ch)) * 520;
      z += expf(p[tid] - m) * p[2 + tid];
    }
    Msh[tid] = m;
    iZsh[tid] = 1.f / z;
  }
  __syncthreads();
  if (tid < 32) {
    int n = tid >> 4, ch = tid & 15;
    cs[n][ch] = expf(part[((size_t)(b * 16 + ch)) * 520 + n] - Msh[n]);
  }
  float M0 = Msh[0], M1 = Msh[1], iZ0 = iZsh[0], iZ1 = iZsh[1];
  {
    float al = alpha[0];
    float a = (al > 20.f) ? al : log1pf(expf(al));
    float k = 0.5f * 1024.f * a;
    for (int i = tid; i < 1024; i += 256) {
      float d0 = scores[((size_t)b * 2 + 0) * 1024 + i];
      float d1 = scores[((size_t)b * 2 + 1) * 1024 + i];
      rowscale[(size_t)b * 1024 + i] = 1.f + k * (expf(d0 - M0) * iZ0 + expf(d1 - M1) * iZ1);
    }
  }
  __syncthreads();
#pragma unroll
  for (int i = 0; i < 2; ++i) {
    int id = tid + i * 256;
    int n = id >> 8, c = id & 255;
    float s = 0.f;
    for (int ch = 0; ch < 16; ++ch)
      s += cs[n][ch] * part[((size_t)(b * 16 + ch)) * 520 + 4 + n * 256 + c];
    xs[id] = s * iZsh[n];
  }
  __syncthreads();
  {
    int d = tid & 127, half = tid >> 7;
    int n = d >> 6;
    const float* xr = xs + n * 256 + half * 128;
    const float* wv = Wv + (size_t)half * 128 * 128 + d;
    float s = 0.f;
#pragma unroll 4
    for (int c = 0; c < 128; ++c) s += xr[c] * wv[(size_t)c * 128];
    phalf[tid] = s;
  }
  __syncthreads();
  if (tid < 128) pooled[tid] = phalf[tid] + phalf[tid + 128];
  __syncthreads();
  if (tid < 4) {
    float s = 0.f;
    for (int d = 0; d < 128; ++d) s += pooled[d] * Wmlp[d * 4 + tid];
    lg[tid] = s;
  }
  __syncthreads();
  if (tid == 0) {
    float al[KK];
    if (step == 0) { for (int k = 0; k < KK; ++k) al[k] = 1.f; }
    else           { for (int k = 0; k < KK; ++k) al[k] = allowed[b * KK + k]; }
    float ml[KK];
    for (int k = 0; k < KK; ++k)
      ml[k] = (al[k] > 0.5f) ? lg[k] * (1.f / 1.5f) : (-1e9f) * (1.f / 1.5f);
    float m = ml[0];
    for (int k = 1; k < KK; ++k) m = fmaxf(m, ml[k]);
    float e[KK], ssum = 0.f;
    for (int k = 0; k < KK; ++k) { e[k] = expf(ml[k] - m); ssum += e[k]; }
    float w[KK];
    for (int k = 0; k < KK; ++k) w[k] = e[k] / ssum;
    int i0 = 0;
    for (int k = 1; k < KK; ++k) if (w[k] > w[i0]) i0 = k;
    int i1 = -1;
    for (int k = 0; k < KK; ++k) {
      if (k == i0) continue;
      if (i1 < 0 || w[k] > w[i1]) i1 = k;
    }
    float denom = w[i0] + w[i1] + 1e-9f;
    selE[b * 2 + 0] = i0;
    selE[b * 2 + 1] = i1;
    selW[b * 2 + 0] = w[i0] / denom;
    selW[b * 2 + 1] = w[i1] / denom;
    if (i0 != KK - 1) al[i0] = fminf(fmaxf(al[i0] - 1.f, 0.f), 1.f);
    al[KK - 1] = fmaxf(al[KK - 1], 1.f);
    for (int k = 0; k < KK; ++k) allowed[b * KK + k] = al[k];
  }
}

// MFMA implicit-GEMM conv, single-f16. Block = 256 thr (4 waves, 2m x 2n),
// M=128 pixels, N=128 cos; wave tile 64x64. x (f16) double-buffered in
// XOR-swizzled LDS. B: register-staged from per-EXPERT f16 tables with
// in-register pk_fma combine (w0*We0 + w1*We1); pipeline shifted so each
// group's vmcnt drains loads issued a FULL group earlier, and the combine
// runs before the MFMA cluster (ds_writes drain under the taps).
__global__ __launch_bounds__(256, 2) void conv_kernel(
    const float* __restrict__ xin, const float* __restrict__ rowscale,
    const unsigned short* __restrict__ Wt,
    const float* __restrict__ be,
    const int* __restrict__ selE, const float* __restrict__ selW,
    float* __restrict__ out) {
  __shared__ __align__(16) unsigned char xsB[2][NCELL * 64];  // 2 x 13056
  __shared__ __align__(16) unsigned char BsB[2][3 * 8192];    // 2 x 24576
  __shared__ float rs_lds[NCELL];                             // 816 B

  int bid = blockIdx.x;
  int xcd = bid & 7, t2b = bid >> 3;
  int mt = t2b & 7, gs = t2b >> 3;
  int g = gs * 8 + xcd;           // (b,nt) group; its 8 mt-blocks share one XCD
  int b = g >> 1, nt = g & 1;
  int h0 = mt * 4;
  int tid = threadIdx.x;
  int lane = tid & 63, wid = tid >> 6;
  int wm = wid >> 1, wn = wid & 1;
  int l15 = lane & 15, kl = lane >> 4;

  int e0 = selE[b * 2], e1 = selE[b * 2 + 1];
  float w0 = selW[b * 2], w1 = selW[b * 2 + 1];
  fp16x2 w0h = {(__fp16)w0, (__fp16)w0};
  fp16x2 w1h = {(__fp16)w1, (__fp16)w1};
  const unsigned short* W0 = Wt + (size_t)e0 * 72 * 8192;
  const unsigned short* W1 = Wt + (size_t)e1 * 72 * 8192;

  int cellb[4];
#pragma unroll
  for (int mf = 0; mf < 4; ++mf) {
    int p0 = wm * 64 + mf * 16;
    cellb[mf] = (p0 >> 5) * XC + (p0 & 31) + l15;
  }
  int bbyte[4];
#pragma unroll
  for (int nf = 0; nf < 4; ++nf) {
    int co = wn * 64 + nf * 16 + l15;
    bbyte[nf] = (co * 64 + kl * 16) ^ ((co & 7) << 4);
  }
  int scol[2], sq[2], sdst[2];
#pragma unroll
  for (int s2 = 0; s2 < 2; ++s2) {
    int u = tid + s2 * 256;
    scol[s2] = u >> 2;
    sq[s2] = u & 3;
    sdst[s2] = (scol[s2] * 64 + sq[s2] * 16) ^ ((scol[s2] & 7) << 4);
  }

  float bias[4];
#pragma unroll
  for (int nf = 0; nf < 4; ++nf) {
    int con = nt * 128 + wn * 64 + nf * 16 + l15;
    bias[nf] = w0 * be[e0 * 256 + con] + w1 * be[e1 * 256 + con];
  }

  f32x4 acc[4][4];
#pragma unroll
  for (int mf = 0; mf < 4; ++mf)
#pragma unroll
    for (int nf = 0; nf < 4; ++nf) acc[mf][nf] = (f32x4){0.f, 0.f, 0.f, 0.f};

  for (int i = tid; i < NCELL; i += 256) {
    int r = i / XC, c = i - r * XC;
    int gr = h0 - 1 + r, gc = c - 1;
    float v = 0.f;
    if (gr >= 0 && gr < 32 && gc >= 0 && gc < 32)
      v = rowscale[(size_t)b * 1024 + gr * 32 + gc];
    rs_lds[i] = v;
  }

  auto stage_x = [&](int kcc) {
    unsigned char* xd = xsB[kcc & 1];
    for (int idx = tid; idx < NCELL * 2; idx += 256) {
      int hk = (idx >= NCELL) ? 1 : 0;
      int cell = idx - hk * NCELL;
      int r = cell / XC, c = cell - r * XC;
      int gr = h0 - 1 + r, gc = c - 1;
      uint4 pk = make_uint4(0, 0, 0, 0), pk2 = make_uint4(0, 0, 0, 0);
      if (gr >= 0 && gr < 32 && gc >= 0 && gc < 32) {
        const float* src = xin + (((size_t)b * 32 + gr) * 32 + gc) * 256 + kcc * 32 + hk * 16;
        float sc = rs_lds[cell];
        float xv[16];
        *(float4*)(xv + 0) = *(const float4*)(src + 0);
        *(float4*)(xv + 4) = *(const float4*)(src + 4);
        *(float4*)(xv + 8) = *(const float4*)(src + 8);
        *(float4*)(xv + 12) = *(const float4*)(src + 12);
        unsigned int u[8];
#pragma unroll
        for (int e2 = 0; e2 < 8; ++e2)
          u[e2] = pk2h(xv[e2 * 2] * sc, xv[e2 * 2 + 1] * sc);
        pk = make_uint4(u[0], u[1], u[2], u[3]);
        pk2 = make_uint4(u[4], u[5], u[6], u[7]);
      }
      int sx = (cell & 7) << 4;
      int b0 = (cell * 64 + hk * 32) ^ sx;
      int b1 = (cell * 64 + hk * 32 + 16) ^ sx;
      *(uint4*)(xd + b0) = pk;
      *(uint4*)(xd + b1) = pk2;
    }
  };

  auto load_group = [&](int kcA, int subBase, uint4* A, uint4* B) {
#pragma unroll
    for (int t = 0; t < 3; ++t) {
      size_t toff = (size_t)((subBase + t) * 8 + kcA) * 8192;
#pragma unroll
      for (int s2 = 0; s2 < 2; ++s2) {
        size_t off = toff + (size_t)(nt * 128 + scol[s2]) * 32 + sq[s2] * 8;
        A[t * 2 + s2] = *(const uint4*)(W0 + off);
        B[t * 2 + s2] = *(const uint4*)(W1 + off);
      }
    }
    SCHED0;
  };

  auto cmb = [&](unsigned int a, unsigned int bq) -> unsigned int {
    fp16x2 ha = __builtin_bit_cast(fp16x2, a);
    fp16x2 hb = __builtin_bit_cast(fp16x2, bq);
    fp16x2 hc = ha * w0h + hb * w1h;
    return __builtin_bit_cast(unsigned int, hc);
  };
  auto combine_write = [&](int buf, const uint4* A, const uint4* B) {
#pragma unroll
    for (int t = 0; t < 3; ++t)
#pragma unroll
      for (int s2 = 0; s2 < 2; ++s2) {
        uint4 a = A[t * 2 + s2], bq = B[t * 2 + s2], r;
        r.x = cmb(a.x, bq.x);
        r.y = cmb(a.y, bq.y);
        r.z = cmb(a.z, bq.z);
        r.w = cmb(a.w, bq.w);
        *(uint4*)(&BsB[buf][t * 8192 + sdst[s2]]) = r;
      }
  };

  auto do_tap = [&](int tap, int tIdx, const unsigned char* xsCur, int buf) {
    const int dy = (tap >= 6) ? 2 : ((tap >= 3) ? 1 : 0);
    const int dx = tap - dy * 3;
    const int dcell = dy * XC + dx;
    const unsigned char* bp = &BsB[buf][tIdx * 8192];
    f16x8 af[4], bf[4];
#pragma unroll
    for (int mf = 0; mf < 4; ++mf) {
      int cell = cellb[mf] + dcell;
      int abyte = (cell * 64 + kl * 16) ^ ((cell & 7) << 4);
      af[mf] = *(const f16x8*)(xsCur + abyte);
    }
#pragma unroll
    for (int nf = 0; nf < 4; ++nf) bf[nf] = *(const f16x8*)(bp + bbyte[nf]);
    __builtin_amdgcn_s_setprio(1);
#pragma unroll
    for (int mf = 0; mf < 4; ++mf)
#pragma unroll
      for (int nf = 0; nf < 4; ++nf)
        acc[mf][nf] = __builtin_amdgcn_mfma_f32_16x16x32_f16(af[mf], bf[nf], acc[mf][nf], 0, 0, 0);
    __builtin_amdgcn_s_setprio(0);
  };

  // ---- prologue: publish G0 (taps 0-2, kc0) into buf 0; preload G1 ----
  uint4 LA[6], LB[6];
  load_group(0, 0, LA, LB);
  __syncthreads();   // rs_lds ready
  stage_x(0);
  S_VMCNT0;
  SCHED0;
  combine_write(0, LA, LB);
  load_group(0, 3, LA, LB);   // G1 = taps 3-5 of kc0
  S_LGKM0;
  SCHED0;
  __builtin_amdgcn_s_barrier();

#pragma unroll 1
  for (int kc = 0; kc < 8; ++kc) {
    const unsigned char* xsCur = xsB[kc & 1];
    const int bX = kc & 1;
    // ---- group A: taps 0-2, reads buf bX; publish G+1 -> bX^1; load G+2 ----
    if (kc < 7) stage_x(kc + 1);
    S_VMCNT0;
    SCHED0;
    combine_write(bX ^ 1, LA, LB);   // taps 3-5 of kc
    load_group(kc, 6, LA, LB);       // taps 6-8 of kc
    do_tap(0, 0, xsCur, bX);
    do_tap(1, 1, xsCur, bX);
    do_tap(2, 2, xsCur, bX);
    S_LGKM0;
    SCHED0;
    __builtin_amdgcn_s_barrier();
    // ---- group B: taps 3-5, reads buf bX^1; publish G+2 -> bX ----
    S_VMCNT0;
    SCHED0;
    combine_write(bX, LA, LB);       // taps 6-8 of kc
    if (kc < 7) load_group(kc + 1, 0, LA, LB);  // taps 0-2 of kc+1
    do_tap(3, 0, xsCur, bX ^ 1);
    do_tap(4, 1, xsCur, bX ^ 1);
    do_tap(5, 2, xsCur, bX ^ 1);
    S_LGKM0;
    SCHED0;
    __builtin_amdgcn_s_barrier();
    // ---- group C: taps 6-8, reads buf bX; publish next-kc G -> bX^1 ----
    if (kc < 7) {
      S_VMCNT0;
      SCHED0;
      combine_write(bX ^ 1, LA, LB); // taps 0-2 of kc+1
      load_group(kc + 1, 3, LA, LB); // taps 3-5 of kc+1
    }
    do_tap(6, 0, xsCur, bX);
    do_tap(7, 1, xsCur, bX);
    do_tap(8, 2, xsCur, bX);
    S_LGKM0;
    SCHED0;
    __builtin_amdgcn_s_barrier();
  }

#pragma unroll
  for (int mf = 0; mf < 4; ++mf) {
    int p0 = wm * 64 + mf * 16;
    int pr = p0 >> 5, pc = p0 & 31;
    size_t rowbase = ((size_t)b * 32 + h0 + pr) * 32;
#pragma unroll
    for (int nf = 0; nf < 4; ++nf) {
      int co = nt * 128 + wn * 64 + nf * 16 + l15;
#pragma unroll
      for (int rr = 0; rr < 4; ++rr) {
        int col = pc + kl * 4 + rr;
        out[(rowbase + col) * 256 + co] = acc[mf][nf][rr] + bias[nf];
      }
    }
  }
}

extern "C" void kernel_launch(void* const* d_in, const int* in_sizes, int n_in,
                              void* d_out, int out_size, void* d_ws, size_t ws_size,
                              hipStream_t stream) {
  const float* x_in  = (const float*)d_in[0];
  const float* q     = (const float*)d_in[1];
  const float* Wk    = (const float*)d_in[2];
  const float* Wv    = (const float*)d_in[3];
  const float* Wmlp  = (const float*)d_in[4];
  const float* alpha = (const float*)d_in[5];
  const float* We    = (const float*)d_in[6];
  const float* be    = (const float*)d_in[7];
  float* out = (float*)d_out;
  float* ws = (float*)d_ws;

  float* qk       = ws;                  // 512
  float* scores   = qk + 512;            // 65536
  float* rowscale = scores + 65536;      // 32768
  float* part     = rowscale + 32768;    // 32*16*520 = 266240
  float* allowed  = part + 266240;       // 128
  float* selW     = allowed + 128;       // 64
  int*   selE     = (int*)(selW + 64);   // 64
  float* xbuf     = selW + 128;          // 8388608 floats
  unsigned short* Wt = (unsigned short*)(xbuf + 8388608);  // 4*72*8192 = 2,359,296 ushorts

  qk_kernel<<<2, 256, 0, stream>>>(Wk, q, qk);
  prep_w_kernel<<<dim3(72, 4), 256, 0, stream>>>(We, Wt);

  const float* step_in[3] = {x_in, out, xbuf};
  float* step_out[3] = {out, xbuf, out};

  for (int t = 0; t < 3; ++t) {
    const float* xc = step_in[t];
    poolpart_kernel<<<dim3(16, 32), 256, 0, stream>>>(xc, qk, scores, part);
    route_kernel<<<32, 256, 0, stream>>>(part, scores, Wv, Wmlp, alpha, allowed, rowscale, selE, selW, t);
    conv_kernel<<<512, 256, 0, stream>>>(xc, rowscale, Wt, be, selE, selW, step_out[t]);
  }
}